// Round 1
// baseline (906.882 us; speedup 1.0000x reference)
//
#include <hip/hip_runtime.h>
#include <stdint.h>
#include <math.h>

// Problem constants (match reference setup_inputs)
#define NB    32768   // batch
#define NSLOT 5       // NR == NW == 5
#define DIM   512     // DR == DW
#define DK    16      // d_k

// Kernel geometry
#define RPB    64               // rows per block
#define TPB    512              // threads per block = 8 waves
#define CH     128              // d-chunk size (floats)
#define NCHUNK 4                // chunks per slot (512/128)
#define NSL    7                // slots processed: q0,q1,k0..k4
#define NIT    (NSL * NCHUNK)   // 28 chunk-iterations
#define ROWSTRIDE (NSLOT * DIM) // 2560 floats between consecutive rows

__device__ __forceinline__ uint32_t rotl32(uint32_t x, uint32_t r) {
  return (x << r) | (x >> (32u - r));
}

// Threefry-2x32, 20 rounds — bit-exact JAX implementation.
__device__ __forceinline__ void threefry2x32_20(uint32_t k0, uint32_t k1,
                                                uint32_t& x0, uint32_t& x1) {
  const uint32_t ks[3] = {k0, k1, k0 ^ k1 ^ 0x1BD11BDAu};
  const uint32_t rotA[4] = {13u, 15u, 26u, 6u};
  const uint32_t rotB[4] = {17u, 29u, 16u, 24u};
  x0 += ks[0];
  x1 += ks[1];
#pragma unroll
  for (int i = 0; i < 5; ++i) {
#pragma unroll
    for (int j = 0; j < 4; ++j) {
      uint32_t r = (i & 1) ? rotB[j] : rotA[j];
      x0 += x1;
      x1 = rotl32(x1, r);
      x1 ^= x0;
    }
    x0 += ks[(i + 1) % 3];
    x1 += ks[(i + 2) % 3] + (uint32_t)(i + 1);
  }
}

__device__ __forceinline__ uint32_t jax_random_bits_part(uint32_t key_lo, uint32_t i) {
  uint32_t x0 = 0u;
  uint32_t x1 = i;
  threefry2x32_20(0u, key_lo, x0, x1);
  return x0 ^ x1;
}

// Thread mapping (compute phase): row = t & 63 (== lane), kgroup kg = t>>6
// (wave-uniform -> scalar weight loads). Each thread accumulates d_k components
// {2*kg, 2*kg+1} of its row's projection over all 512 d, chunk by chunk.
//
// LDS layout per chunk buffer: buf[row][128] floats (512 B rows, linear), with
// float4 position swizzle p = d4 ^ (row & 7) applied on BOTH ds_write and
// ds_read sides -> conflict-free ds_read_b128 (8 consecutive lanes tile all
// 32 banks) despite the 512 B row stride.
__global__ __launch_bounds__(TPB) void csa_kernel(
    const float* __restrict__ q,   // [NB, NSLOT, DIM]
    const float* __restrict__ kin, // [NB, NSLOT, DIM]
    const float* __restrict__ wr,  // [NSLOT, DIM, DK]
    const float* __restrict__ ww,  // [NSLOT, DIM, DK]
    float* __restrict__ out)       // [2, NB, NSLOT]
{
  __shared__ __align__(16) float buf[2][RPB * CH];   // 2 x 32 KB double buffer

  const int t      = threadIdx.x;
  const int lane   = t & 63;                                   // compute row
  const int kg     = __builtin_amdgcn_readfirstlane(t >> 6);   // wave-uniform
  const int c0     = kg * 2;                                   // my 2 comps
  const int r7     = lane & 7;
  const int row_g0 = blockIdx.x * RPB;

  // staging indices: float4 f4 = jj*512 + t over the chunk's 2048 float4s
  const int t5  = t >> 5;    // (f4 >> 5) - jj*16
  const int d4s = t & 31;    // f4 & 31 (jj*512 is a multiple of 32)

  float rcomp[2][2];   // read-projection comps (slots 0,1)
  float pscr[10];      // partial scores [n*5+m] over my 2 comps
  float acc0 = 0.f, acc1 = 0.f;

  auto aslot = [&](int s) -> const float* {
    return (s < 2) ? (q + (size_t)row_g0 * ROWSTRIDE + s * DIM)
                   : (kin + (size_t)row_g0 * ROWSTRIDE + (s - 2) * DIM);
  };

  float4 sreg[4];

  // ---- prologue: stage chunk 0 (slot 0, c 0) ----
  {
    const float* ab = aslot(0);
#pragma unroll
    for (int jj = 0; jj < 4; ++jj) {
      int sr = jj * 16 + t5;
      sreg[jj] = *(const float4*)(ab + (size_t)sr * ROWSTRIDE + d4s * 4);
    }
#pragma unroll
    for (int jj = 0; jj < 4; ++jj) {
      int sr = jj * 16 + t5;
      *(float4*)(&buf[0][sr * CH + ((d4s ^ (sr & 7)) << 2)]) = sreg[jj];
    }
  }
  __syncthreads();

#pragma unroll 1
  for (int it = 0; it < NIT; ++it) {
    const int s   = it >> 2;
    const int c   = it & 3;
    const int nit = it + 1;

    // issue next chunk's global loads early (latency hides under compute)
    if (nit < NIT) {
      const int ns = nit >> 2, nc = nit & 3;
      const float* ab = aslot(ns) + nc * CH;
#pragma unroll
      for (int jj = 0; jj < 4; ++jj) {
        int sr = jj * 16 + t5;
        sreg[jj] = *(const float4*)(ab + (size_t)sr * ROWSTRIDE + d4s * 4);
      }
    }

    // ---- compute on buf[it&1]: 128 d x 2 comps ----
    {
      const float* wsl = (s < 2) ? (wr + s * (DIM * DK)) : (ww + (s - 2) * (DIM * DK));
      const float* wp  = wsl + c * (CH * DK) + c0;   // wave-uniform address
      const float* bp  = &buf[it & 1][lane * CH];
#pragma unroll
      for (int d4 = 0; d4 < 32; ++d4) {
        const float4 av = *(const float4*)(bp + ((d4 ^ r7) << 2));
        const float* wd = wp + d4 * 4 * DK;
        float2 w0 = *(const float2*)(wd + 0 * DK);
        float2 w1 = *(const float2*)(wd + 1 * DK);
        float2 w2 = *(const float2*)(wd + 2 * DK);
        float2 w3 = *(const float2*)(wd + 3 * DK);
        acc0 = fmaf(av.x, w0.x, acc0); acc1 = fmaf(av.x, w0.y, acc1);
        acc0 = fmaf(av.y, w1.x, acc0); acc1 = fmaf(av.y, w1.y, acc1);
        acc0 = fmaf(av.z, w2.x, acc0); acc1 = fmaf(av.z, w2.y, acc1);
        acc0 = fmaf(av.w, w3.x, acc0); acc1 = fmaf(av.w, w3.y, acc1);
      }
    }

    // slot boundary: commit projection comps / partial scores
    if (c == 3) {
      if (s < 2) {
        rcomp[s][0] = acc0; rcomp[s][1] = acc1;
      } else {
        const int m = s - 2;
        pscr[0 * NSLOT + m] = rcomp[0][0] * acc0 + rcomp[0][1] * acc1;
        pscr[1 * NSLOT + m] = rcomp[1][0] * acc0 + rcomp[1][1] * acc1;
      }
      acc0 = 0.f; acc1 = 0.f;
    }

    // write staged regs into the other buffer (it was free since last barrier)
    if (nit < NIT) {
      float* bd = &buf[nit & 1][0];
#pragma unroll
      for (int jj = 0; jj < 4; ++jj) {
        int sr = jj * 16 + t5;
        *(float4*)(bd + sr * CH + ((d4s ^ (sr & 7)) << 2)) = sreg[jj];
      }
    }
    __syncthreads();
  }

  // ---- cross-kgroup score reduction (reuse buf[0] region: 8x64x10 floats) ----
  float* psc = &buf[0][0];
  {
    float* pd = psc + (kg * RPB + lane) * 10;
#pragma unroll
    for (int j = 0; j < 10; ++j) pd[j] = pscr[j];
  }
  __syncthreads();

  if (t < RPB) {
    const int row_g = row_g0 + t;
    float sc[10];
#pragma unroll
    for (int j = 0; j < 10; ++j) {
      float sum = 0.f;
#pragma unroll
      for (int g = 0; g < 8; ++g) sum += psc[(g * RPB + t) * 10 + j];
      sc[j] = sum * 0.25f;   // exact /sqrt(16)
    }
#pragma unroll
    for (int n = 0; n < 2; ++n) {
      const uint32_t key_lo = (n == 0) ? 42u : 43u;
      int best = 0;
      float bestv = -INFINITY;
#pragma unroll
      for (int m = 0; m < NSLOT; ++m) {
        uint32_t i = (uint32_t)(row_g * NSLOT + m);
        uint32_t bits = jax_random_bits_part(key_lo, i);
        float f = __uint_as_float((bits >> 9) | 0x3F800000u) - 1.0f;
        float u = fmaxf(1e-10f, f + 1e-10f);
        double tt = -log((double)u);
        float gmb = (float)(-log(tt));
        float z = sc[n * NSLOT + m] + gmb;   // tau == 1.0
        if (z > bestv) { bestv = z; best = m; }  // first-max tiebreak
      }
      float* o = out + (size_t)n * (NB * NSLOT) + (size_t)row_g * NSLOT;
#pragma unroll
      for (int m = 0; m < NSLOT; ++m) o[m] = (m == best) ? 1.0f : 0.0f;
    }
  }
}

extern "C" void kernel_launch(void* const* d_in, const int* in_sizes, int n_in,
                              void* d_out, int out_size, void* d_ws, size_t ws_size,
                              hipStream_t stream) {
  const float* q  = (const float*)d_in[0];
  const float* k  = (const float*)d_in[1];
  const float* wr = (const float*)d_in[2];
  const float* ww = (const float*)d_in[3];
  float* out = (float*)d_out;

  dim3 grid(NB / RPB);   // 512 blocks, 2 per CU (64 KB LDS each)
  dim3 block(TPB);
  csa_kernel<<<grid, block, 0, stream>>>(q, k, wr, ww, out);
}

// Round 3
// 844.415 us; speedup vs baseline: 1.0740x; 1.0740x over previous
//
#include <hip/hip_runtime.h>
#include <stdint.h>
#include <math.h>

// Problem constants (match reference setup_inputs)
#define NB    32768   // batch
#define NSLOT 5       // NR == NW == 5
#define DIM   512     // DR == DW
#define DK    16      // d_k

// Kernel geometry
#define RPB    64               // rows per block
#define TPB    512              // threads per block = 8 waves
#define CH     128              // d-chunk size (floats)
#define NSL    7                // slots processed: q0,q1,k0..k4
#define ROWSTRIDE (NSLOT * DIM) // 2560 floats between consecutive rows

__device__ __forceinline__ uint32_t rotl32(uint32_t x, uint32_t r) {
  return (x << r) | (x >> (32u - r));
}

// Threefry-2x32, 20 rounds — bit-exact JAX implementation.
__device__ __forceinline__ void threefry2x32_20(uint32_t k0, uint32_t k1,
                                                uint32_t& x0, uint32_t& x1) {
  const uint32_t ks[3] = {k0, k1, k0 ^ k1 ^ 0x1BD11BDAu};
  const uint32_t rotA[4] = {13u, 15u, 26u, 6u};
  const uint32_t rotB[4] = {17u, 29u, 16u, 24u};
  x0 += ks[0];
  x1 += ks[1];
#pragma unroll
  for (int i = 0; i < 5; ++i) {
#pragma unroll
    for (int j = 0; j < 4; ++j) {
      uint32_t r = (i & 1) ? rotB[j] : rotA[j];
      x0 += x1;
      x1 = rotl32(x1, r);
      x1 ^= x0;
    }
    x0 += ks[(i + 1) % 3];
    x1 += ks[(i + 2) % 3] + (uint32_t)(i + 1);
  }
}

__device__ __forceinline__ uint32_t jax_random_bits_part(uint32_t key_lo, uint32_t i) {
  uint32_t x0 = 0u;
  uint32_t x1 = i;
  threefry2x32_20(0u, key_lo, x0, x1);
  return x0 ^ x1;
}

// Async global->LDS, 16 B per lane. LDS dest is wave-uniform base + lane*16
// (HW rule); swizzled layout comes from pre-swizzling the GLOBAL source
// address per lane (rule #21: linear dest + inverse-swz source + swz read).
__device__ __forceinline__ void gload_lds16(const float* g, float* l) {
  __builtin_amdgcn_global_load_lds(
      (const __attribute__((address_space(1))) void*)g,
      (__attribute__((address_space(3))) void*)l, 16, 0, 0);
}

// stage one 64x128 chunk: src = (block row0, slot, chunk) origin; goff is the
// per-thread pre-swizzled source offset (floats); dst = chunk buffer base;
// kg = wave index (uniform). Thread t covers float4 f = jj*512 + t:
// row sr = jj*16 + (t>>5), dest pos p = t&31 holding element p ^ (sr&7).
__device__ __forceinline__ void stage_chunk(const float* src, size_t goff,
                                            float* dst, int kg) {
#pragma unroll
  for (int jj = 0; jj < 4; ++jj) {
    gload_lds16(src + goff + (size_t)jj * (16 * ROWSTRIDE),
                dst + jj * 2048 + kg * 256);
  }
}

// Thread mapping (compute): row = t & 63, kgroup kg = t>>6 (wave-uniform ->
// scalar weight loads). Each thread accumulates d_k comps {2kg, 2kg+1}.
// LDS layout: buf[row][128]; float4 position p holds global element p^(row&7);
// reader fetches element d4 at position d4^(row&7).
__global__ __launch_bounds__(TPB, 2) void csa_kernel(
    const float* __restrict__ q,   // [NB, NSLOT, DIM]
    const float* __restrict__ kin, // [NB, NSLOT, DIM]
    const float* __restrict__ wr,  // [NSLOT, DIM, DK]
    const float* __restrict__ ww,  // [NSLOT, DIM, DK]
    float* __restrict__ out)       // [2, NB, NSLOT]
{
  __shared__ __align__(16) float buf[2][RPB * CH];   // 2 x 32 KB double buffer

  const int t      = threadIdx.x;
  const int lane   = t & 63;                                   // compute row
  const int kg     = __builtin_amdgcn_readfirstlane(t >> 6);   // wave-uniform
  const int c0     = kg * 2;
  const int r7     = lane & 7;
  const int row_g0 = blockIdx.x * RPB;
  const size_t base = (size_t)row_g0 * ROWSTRIDE;

  // per-thread pre-swizzled staging source offset (jj-invariant):
  // sr&7 == (t>>5)&7 because jj*16 % 8 == 0.
  const int t5    = t >> 5;
  const int d4src = (t & 31) ^ (t5 & 7);
  const size_t goff = (size_t)t5 * ROWSTRIDE + (size_t)(d4src * 4); // floats

  float rcomp[2][2];   // read-projection comps (slots 0,1) — static-indexed
  float pscr[10];      // partial scores [n*5+m] — static-indexed
  float acc0 = 0.f, acc1 = 0.f;

  // ---- prologue: stage chunk 0 (slot 0, c 0) into buf[0] ----
  stage_chunk(q + base, goff, &buf[0][0], kg);
  __syncthreads();

#pragma unroll
  for (int s = 0; s < NSL; ++s) {
    const float* asrc  = (s < 2) ? (q + base + (size_t)s * DIM)
                                 : (kin + base + (size_t)(s - 2) * DIM);
    const float* wslot = (s < 2) ? (wr + s * (DIM * DK))
                                 : (ww + (s - 2) * (DIM * DK));
#pragma unroll 1
    for (int c = 0; c < 4; ++c) {
      // prefetch next chunk (async; compiler drains vmcnt(0) at the barrier)
      if (c < 3) {
        stage_chunk(asrc + (size_t)(c + 1) * CH, goff,
                    &buf[(c + 1) & 1][0], kg);
      } else if (s < NSL - 1) {
        const float* nsrc = (s + 1 < 2) ? (q + base + (size_t)(s + 1) * DIM)
                                        : (kin + base + (size_t)(s - 1) * DIM);
        stage_chunk(nsrc, goff, &buf[(c + 1) & 1][0], kg);
      }

      // compute on buf[c&1] (parity of it = (4s+c)&1 = c&1)
      {
        const float* bp = &buf[c & 1][lane * CH];
        const float* wp = wslot + c * (CH * DK) + c0;   // wave-uniform
#pragma unroll
        for (int d4 = 0; d4 < 32; ++d4) {
          const float4 av = *(const float4*)(bp + ((d4 ^ r7) << 2));
          const float* wd = wp + d4 * (4 * DK);
          float2 w0 = *(const float2*)(wd + 0 * DK);
          float2 w1 = *(const float2*)(wd + 1 * DK);
          float2 w2 = *(const float2*)(wd + 2 * DK);
          float2 w3 = *(const float2*)(wd + 3 * DK);
          acc0 = fmaf(av.x, w0.x, acc0); acc1 = fmaf(av.x, w0.y, acc1);
          acc0 = fmaf(av.y, w1.x, acc0); acc1 = fmaf(av.y, w1.y, acc1);
          acc0 = fmaf(av.z, w2.x, acc0); acc1 = fmaf(av.z, w2.y, acc1);
          acc0 = fmaf(av.w, w3.x, acc0); acc1 = fmaf(av.w, w3.y, acc1);
        }
      }
      __syncthreads();
    }

    // slot boundary: commit with STATIC s (stays in registers)
    if (s == 0)      { rcomp[0][0] = acc0; rcomp[0][1] = acc1; }
    else if (s == 1) { rcomp[1][0] = acc0; rcomp[1][1] = acc1; }
    else {
      const int m = s - 2;
      pscr[0 * NSLOT + m] = rcomp[0][0] * acc0 + rcomp[0][1] * acc1;
      pscr[1 * NSLOT + m] = rcomp[1][0] * acc0 + rcomp[1][1] * acc1;
    }
    acc0 = 0.f; acc1 = 0.f;
  }

  // ---- cross-kgroup score reduction (reuse buf[0]: 8x64x10 floats = 20 KB) ----
  float* psc = &buf[0][0];
  {
    float* pd = psc + (kg * RPB + lane) * 10;
#pragma unroll
    for (int j = 0; j < 10; ++j) pd[j] = pscr[j];
  }
  __syncthreads();

  if (t < RPB) {
    const int row_g = row_g0 + t;
    float sc[10];
#pragma unroll
    for (int j = 0; j < 10; ++j) {
      float sum = 0.f;
#pragma unroll
      for (int g = 0; g < 8; ++g) sum += psc[(g * RPB + t) * 10 + j];
      sc[j] = sum * 0.25f;   // exact /sqrt(16)
    }
#pragma unroll
    for (int n = 0; n < 2; ++n) {
      const uint32_t key_lo = (n == 0) ? 42u : 43u;
      int best = 0;
      float bestv = -INFINITY;
#pragma unroll
      for (int m = 0; m < NSLOT; ++m) {
        uint32_t i = (uint32_t)(row_g * NSLOT + m);
        uint32_t bits = jax_random_bits_part(key_lo, i);
        float f = __uint_as_float((bits >> 9) | 0x3F800000u) - 1.0f;
        float u = fmaxf(1e-10f, f + 1e-10f);
        double tt = -log((double)u);
        float gmb = (float)(-log(tt));
        float z = sc[n * NSLOT + m] + gmb;   // tau == 1.0
        if (z > bestv) { bestv = z; best = m; }  // first-max tiebreak
      }
      float* o = out + (size_t)n * (NB * NSLOT) + (size_t)row_g * NSLOT;
#pragma unroll
      for (int m = 0; m < NSLOT; ++m) o[m] = (m == best) ? 1.0f : 0.0f;
    }
  }
}

extern "C" void kernel_launch(void* const* d_in, const int* in_sizes, int n_in,
                              void* d_out, int out_size, void* d_ws, size_t ws_size,
                              hipStream_t stream) {
  const float* q  = (const float*)d_in[0];
  const float* k  = (const float*)d_in[1];
  const float* wr = (const float*)d_in[2];
  const float* ww = (const float*)d_in[3];
  float* out = (float*)d_out;

  dim3 grid(NB / RPB);   // 512 blocks; LDS 64 KB -> 2 blocks/CU, 16 waves/CU
  dim3 block(TPB);
  csa_kernel<<<grid, block, 0, stream>>>(q, k, wr, ww, out);
}